// Round 1
// baseline (18157.185 us; speedup 1.0000x reference)
//
#include <hip/hip_runtime.h>
#include <math.h>

#define EPS_ 1e-5f

// ---------------- reduction helpers ----------------
__device__ inline float wred_sum(float v){
#pragma unroll
  for(int o=32;o>=1;o>>=1) v += __shfl_xor(v,o);
  return v;
}
__device__ inline float wred_max(float v){
#pragma unroll
  for(int o=32;o>=1;o>>=1) v = fmaxf(v,__shfl_xor(v,o));
  return v;
}
// block(256) reduce; sm must have 4 floats
__device__ inline float bred256_sum(float v, float* sm){
  v = wred_sum(v);
  if((threadIdx.x&63)==0) sm[threadIdx.x>>6]=v;
  __syncthreads();
  v = sm[0]+sm[1]+sm[2]+sm[3];
  __syncthreads();
  return v;
}
__device__ inline float bred256_max(float v, float* sm){
  v = wred_max(v);
  if((threadIdx.x&63)==0) sm[threadIdx.x>>6]=v;
  __syncthreads();
  v = fmaxf(fmaxf(sm[0],sm[1]),fmaxf(sm[2],sm[3]));
  __syncthreads();
  return v;
}

// ---------------- generic tiled fp32 GEMM ----------------
// C = alpha * (A @ op(W)) [+ bias] with epilogues.
// A: [M,K], row stride lda.  !WT: W is [N,K] (we compute A@W^T). WT: W is [K,N].
// Batched via blockIdx.z: off = (z/nInner)*s?o + (z%nInner)*s?i.
// EPI: 0 store; 1 store + aux[(m%196)*384+n] (pos-embed); 2 C[m,n] += aux[n]*v (LayerScale residual); 3 store gelu(v)
template<bool WT,int EPI>
__global__ __launch_bounds__(256) void gemm_f32(
    const float* __restrict__ A,int lda,long sAo,long sAi,
    const float* __restrict__ W,int ldw,long sWo,long sWi,
    const float* __restrict__ bias,
    float* __restrict__ C,int ldc,long sCo,long sCi,
    int M,int N,int K,int nInner,float alpha,
    const float* __restrict__ aux)
{
  __shared__ float As[16][65];
  __shared__ float Ws[16][65];
  int z = blockIdx.z;
  int zo = z / nInner, zi = z % nInner;
  const float* Ab = A + zo*sAo + zi*sAi;
  const float* Wb = W + zo*sWo + zi*sWi;
  float* Cb = C + zo*sCo + zi*sCi;
  int t = threadIdx.x;
  int tx = t & 15, ty = t >> 4;
  int m0 = blockIdx.y*64, n0 = blockIdx.x*64;
  float acc[4][4] = {};
  for(int k0=0;k0<K;k0+=16){
#pragma unroll
    for(int p=0;p<4;++p){
      int row = p*16 + ty;
      int gm = m0+row, gk = k0+tx;
      As[tx][row] = (gm<M && gk<K) ? Ab[(long)gm*lda+gk] : 0.f;
      if(!WT){
        int gn = n0+row;
        Ws[tx][row] = (gn<N && gk<K) ? Wb[(long)gn*ldw+gk] : 0.f;
      } else {
        int idx = p*256+t, kk = idx>>6, col = idx&63;
        int gk2 = k0+kk, gn2 = n0+col;
        Ws[kk][col] = (gn2<N && gk2<K) ? Wb[(long)gk2*ldw+gn2] : 0.f;
      }
    }
    __syncthreads();
#pragma unroll
    for(int kk=0;kk<16;++kk){
      float a[4],b[4];
#pragma unroll
      for(int i=0;i<4;++i) a[i]=As[kk][ty*4+i];
#pragma unroll
      for(int j=0;j<4;++j) b[j]=Ws[kk][tx*4+j];
#pragma unroll
      for(int i=0;i<4;++i)
#pragma unroll
        for(int j=0;j<4;++j) acc[i][j] += a[i]*b[j];
    }
    __syncthreads();
  }
#pragma unroll
  for(int i=0;i<4;++i){
    int m = m0+ty*4+i; if(m>=M) continue;
#pragma unroll
    for(int j=0;j<4;++j){
      int n = n0+tx*4+j; if(n>=N) continue;
      float v = acc[i][j]*alpha;
      if(bias) v += bias[n];
      if(EPI==1) v += aux[(long)(m%196)*384+n];
      if(EPI==3) v = 0.5f*v*(1.f+erff(v*0.70710678118f));
      if(EPI==2) Cb[(long)m*ldc+n] += aux[n]*v;
      else       Cb[(long)m*ldc+n] = v;
    }
  }
}

// ---------------- LayerNorm over 384 cols ----------------
__global__ __launch_bounds__(128) void ln_kernel(
  const float* __restrict__ X, float* __restrict__ Y,
  const float* __restrict__ g, const float* __restrict__ b, int rows)
{
  int r = blockIdx.x; if(r>=rows) return;
  int t = threadIdx.x;
  const float* xr = X + (long)r*384;
  float* yr = Y + (long)r*384;
  float x0=xr[t], x1=xr[t+128], x2=xr[t+256];
  __shared__ float sm[2];
  float s = x0+x1+x2;
  s = wred_sum(s);
  if((t&63)==0) sm[t>>6]=s;
  __syncthreads();
  float mean = (sm[0]+sm[1])*(1.f/384.f);
  __syncthreads();
  float d0=x0-mean,d1=x1-mean,d2=x2-mean;
  float ss = d0*d0+d1*d1+d2*d2;
  ss = wred_sum(ss);
  if((t&63)==0) sm[t>>6]=ss;
  __syncthreads();
  float rstd = rsqrtf((sm[0]+sm[1])*(1.f/384.f)+EPS_);
  yr[t]     = d0*rstd*g[t]    +b[t];
  yr[t+128] = d1*rstd*g[t+128]+b[t+128];
  yr[t+256] = d2*rstd*g[t+256]+b[t+256];
}

// ---------------- talking-heads mix + softmax + mix, in place ----------------
// one block per (b, n); 8 heads held in registers per m-column owner thread
__global__ __launch_bounds__(256) void th_softmax(
  float* __restrict__ attn,
  const float* __restrict__ plw, const float* __restrict__ plb,
  const float* __restrict__ pww, const float* __restrict__ pwb)
{
  int bn = blockIdx.x;
  int b = bn/196, n = bn%196;
  int t = threadIdx.x;
  __shared__ float swl[64], sww[64], sbl[8], sbw[8], sm[4];
  if(t<64){ swl[t]=plw[t]; sww[t]=pww[t]; }
  if(t<8){ sbl[t]=plb[t]; sbw[t]=pwb[t]; }
  __syncthreads();
  bool act = t<196;
  long base = (long)b*8*38416 + (long)n*196 + t;
  float L[8];
#pragma unroll
  for(int h=0;h<8;++h) L[h] = act ? attn[base + (long)h*38416] : 0.f;
  float soft[8];
#pragma unroll
  for(int g=0; g<8; ++g){
    float v = sbl[g];
#pragma unroll
    for(int h=0;h<8;++h) v += L[h]*swl[g*8+h];
    if(!act) v = -3.0e38f;
    float mx = bred256_max(v, sm);
    float e = act ? expf(v-mx) : 0.f;
    float ssum = bred256_sum(e, sm);
    soft[g] = e/ssum;
  }
#pragma unroll
  for(int g2=0; g2<8; ++g2){
    float v = sbw[g2];
#pragma unroll
    for(int g=0; g<8; ++g) v += soft[g]*sww[g2*8+g];
    if(act) attn[base + (long)g2*38416] = v;
  }
}

// ---------------- class-attention (1 query token) ----------------
__global__ __launch_bounds__(256) void ca_attn_kernel(
  const float* __restrict__ q, const float* __restrict__ k,
  const float* __restrict__ v, float* __restrict__ o)
{
  int bh = blockIdx.x; int b = bh>>3, h = bh&7;
  int t = threadIdx.x;
  __shared__ float qs[48], p[197], sm[4];
  if(t<48) qs[t] = q[(long)b*384 + h*48 + t];
  __syncthreads();
  float logit = -3.0e38f;
  if(t<197){
    const float* kr = k + ((long)(b*197+t))*384 + h*48;
    float s=0.f;
#pragma unroll
    for(int d=0;d<48;++d) s += qs[d]*kr[d];
    logit = s;
  }
  float mx = bred256_max(logit, sm);
  float e = (t<197)? expf(logit-mx):0.f;
  float ssum = bred256_sum(e, sm);
  if(t<197) p[t] = e/ssum;
  __syncthreads();
  if(t<48){
    const float* vr = v + (long)b*197*384 + h*48 + t;
    float s=0.f;
    for(int m=0;m<197;++m) s += p[m]*vr[(long)m*384];
    o[(long)b*384 + h*48 + t] = s;
  }
}

// ---------------- small elementwise kernels ----------------
__global__ void patch_extract(const float* __restrict__ x, float* __restrict__ xp){
  long i = (long)blockIdx.x*256 + threadIdx.x;
  if(i >= (long)12544*768) return;
  int k = (int)(i % 768); long row = i/768;
  int b = (int)(row/196), pidx = (int)(row%196);
  int gy = pidx/14, gx = pidx%14;
  int ch = k/256, r = k%256, py = r/16, px = r%16;
  xp[i] = x[((long)(b*3+ch)*224 + gy*16+py)*224 + gx*16+px];
}
__global__ void build_u(const float* __restrict__ h, float* __restrict__ u){
  long i = (long)blockIdx.x*256 + threadIdx.x;
  if(i >= (long)12544*384) return;
  int c = (int)(i % 384); long rp = i/384;
  int b = (int)(rp/196), p = (int)(rp%196);
  u[((long)b*197 + 1 + p)*384 + c] = h[i];
}
__global__ void set_row0(float* __restrict__ u, const float* __restrict__ cls){
  int i = blockIdx.x*256 + threadIdx.x;
  if(i >= 64*384) return;
  int b = i/384, c = i%384;
  u[(long)b*197*384 + c] = cls[i];
}
__global__ void init_cls(float* __restrict__ cls, const float* __restrict__ tok){
  int i = blockIdx.x*256 + threadIdx.x;
  if(i >= 64*384) return;
  cls[i] = tok[i%384];
}

// ---------------- host orchestration ----------------
extern "C" void kernel_launch(void* const* d_in, const int* in_sizes, int n_in,
                              void* d_out, int out_size, void* d_ws, size_t ws_size,
                              hipStream_t stream)
{
  const float* in_x     = (const float*)d_in[0];
  const float* patch_w  = (const float*)d_in[1];
  const float* patch_b  = (const float*)d_in[2];
  const float* cls_tok  = (const float*)d_in[3];
  const float* pos_emb  = (const float*)d_in[4];
  const float* ln1_g = (const float*)d_in[5];
  const float* ln1_b = (const float*)d_in[6];
  const float* qkv_w = (const float*)d_in[7];
  const float* proj_w = (const float*)d_in[8];
  const float* proj_b = (const float*)d_in[9];
  const float* pl_w = (const float*)d_in[10];
  const float* pl_b = (const float*)d_in[11];
  const float* pw_w = (const float*)d_in[12];
  const float* pw_b = (const float*)d_in[13];
  const float* ln2_g = (const float*)d_in[14];
  const float* ln2_b = (const float*)d_in[15];
  const float* fc1_w = (const float*)d_in[16];
  const float* fc1_b = (const float*)d_in[17];
  const float* fc2_w = (const float*)d_in[18];
  const float* fc2_b = (const float*)d_in[19];
  const float* g1 = (const float*)d_in[20];
  const float* g2 = (const float*)d_in[21];
  const float* ca_ln1_g = (const float*)d_in[22];
  const float* ca_ln1_b = (const float*)d_in[23];
  const float* ca_q_w = (const float*)d_in[24];
  const float* ca_k_w = (const float*)d_in[25];
  const float* ca_v_w = (const float*)d_in[26];
  const float* ca_proj_w = (const float*)d_in[27];
  const float* ca_proj_b = (const float*)d_in[28];
  const float* ca_ln2_g = (const float*)d_in[29];
  const float* ca_ln2_b = (const float*)d_in[30];
  const float* ca_fc1_w = (const float*)d_in[31];
  const float* ca_fc1_b = (const float*)d_in[32];
  const float* ca_fc2_w = (const float*)d_in[33];
  const float* ca_fc2_b = (const float*)d_in[34];
  const float* ca_g1 = (const float*)d_in[35];
  const float* ca_g2 = (const float*)d_in[36];
  const float* norm_g = (const float*)d_in[37];
  const float* norm_b = (const float*)d_in[38];
  const float* head_w = (const float*)d_in[39];
  const float* head_b = (const float*)d_in[40];
  float* out = (float*)d_out;

  float* ws = (float*)d_ws;
  float* h_buf    = ws;                       // 12544*384          = 4,816,896
  float* ln_buf   = h_buf   + 4816896;        // 12608*384          = 4,841,472
  float* o_buf    = ln_buf  + 4841472;        // o-concat / k_ca    = 4,841,472
  float* big_buf  = o_buf   + 4841472;        // qkv / mlp / v_ca   = 19,267,584
  float* attn_buf = big_buf + 19267584;       // attn / xp / u      = 19,668,992
  float* cls_buf  = attn_buf+ 19668992;       // 64*384
  float* qca_buf  = cls_buf + 24576;
  float* oca_buf  = qca_buf + 24576;
  float* clsln_buf= oca_buf + 24576;
  float* mlpca_buf= clsln_buf+24576;          // 64*1536

  const float scl = 0.14433756729740643f;     // 48^-0.5
  dim3 blk(256);

  // 1. patch extract (xp into attn_buf) + patch GEMM (+bias +pos_embed)
  {
    long n = (long)12544*768;
    patch_extract<<<dim3((unsigned)((n+255)/256)), blk, 0, stream>>>(in_x, attn_buf);
  }
  gemm_f32<false,1><<<dim3(6,196,1),blk,0,stream>>>(attn_buf,768,0,0, patch_w,768,0,0, patch_b,
      h_buf,384,0,0, 12544,384,768,1, 1.f, pos_emb);

  // 2. twelve talking-heads SA blocks
  for(int d=0; d<12; ++d){
    ln_kernel<<<12544,128,0,stream>>>(h_buf, ln_buf, ln1_g+d*384, ln1_b+d*384, 12544);
    gemm_f32<false,0><<<dim3(18,196,1),blk,0,stream>>>(ln_buf,384,0,0, qkv_w+(long)d*1152*384,384,0,0, nullptr,
        big_buf,1152,0,0, 12544,1152,384,1, 1.f, nullptr);
    // logits = scale * q @ k^T, batched over (b,h)
    gemm_f32<false,0><<<dim3(4,4,512),blk,0,stream>>>(big_buf,1152,225792L,48L, big_buf+384,1152,225792L,48L, nullptr,
        attn_buf,196,307328L,38416L, 196,196,48,8, scl, nullptr);
    th_softmax<<<12544,blk,0,stream>>>(attn_buf, pl_w+d*64, pl_b+d*8, pw_w+d*64, pw_b+d*8);
    // o = attn @ v  (W is [K,N] -> WT)
    gemm_f32<true,0><<<dim3(1,4,512),blk,0,stream>>>(attn_buf,196,307328L,38416L, big_buf+768,1152,225792L,48L, nullptr,
        o_buf,384,75264L,48L, 196,48,196,8, 1.f, nullptr);
    // proj + LayerScale residual into h
    gemm_f32<false,2><<<dim3(6,196,1),blk,0,stream>>>(o_buf,384,0,0, proj_w+(long)d*147456,384,0,0, proj_b+d*384,
        h_buf,384,0,0, 12544,384,384,1, 1.f, g1+d*384);
    ln_kernel<<<12544,128,0,stream>>>(h_buf, ln_buf, ln2_g+d*384, ln2_b+d*384, 12544);
    gemm_f32<false,3><<<dim3(24,196,1),blk,0,stream>>>(ln_buf,384,0,0, fc1_w+(long)d*589824,384,0,0, fc1_b+d*1536,
        big_buf,1536,0,0, 12544,1536,384,1, 1.f, nullptr);
    gemm_f32<false,2><<<dim3(6,196,1),blk,0,stream>>>(big_buf,1536,0,0, fc2_w+(long)d*589824,1536,0,0, fc2_b+d*384,
        h_buf,384,0,0, 12544,384,1536,1, 1.f, g2+d*384);
  }

  // 3. two class-attention blocks
  init_cls<<<96,blk,0,stream>>>(cls_buf, cls_tok);
  build_u<<<dim3((unsigned)(((long)12544*384+255)/256)),blk,0,stream>>>(h_buf, attn_buf);
  for(int d=0; d<2; ++d){
    set_row0<<<96,blk,0,stream>>>(attn_buf, cls_buf);
    ln_kernel<<<12608,128,0,stream>>>(attn_buf, ln_buf, ca_ln1_g+d*384, ca_ln1_b+d*384, 12608);
    // q from cls rows only (row stride 197*384), pre-scaled
    gemm_f32<false,0><<<dim3(6,1,1),blk,0,stream>>>(ln_buf,75648,0,0, ca_q_w+(long)d*147456,384,0,0, nullptr,
        qca_buf,384,0,0, 64,384,384,1, scl, nullptr);
    gemm_f32<false,0><<<dim3(6,197,1),blk,0,stream>>>(ln_buf,384,0,0, ca_k_w+(long)d*147456,384,0,0, nullptr,
        o_buf,384,0,0, 12608,384,384,1, 1.f, nullptr);
    gemm_f32<false,0><<<dim3(6,197,1),blk,0,stream>>>(ln_buf,384,0,0, ca_v_w+(long)d*147456,384,0,0, nullptr,
        big_buf,384,0,0, 12608,384,384,1, 1.f, nullptr);
    ca_attn_kernel<<<512,blk,0,stream>>>(qca_buf, o_buf, big_buf, oca_buf);
    gemm_f32<false,2><<<dim3(6,1,1),blk,0,stream>>>(oca_buf,384,0,0, ca_proj_w+(long)d*147456,384,0,0, ca_proj_b+d*384,
        cls_buf,384,0,0, 64,384,384,1, 1.f, ca_g1+d*384);
    ln_kernel<<<64,128,0,stream>>>(cls_buf, clsln_buf, ca_ln2_g+d*384, ca_ln2_b+d*384, 64);
    gemm_f32<false,3><<<dim3(24,1,1),blk,0,stream>>>(clsln_buf,384,0,0, ca_fc1_w+(long)d*589824,384,0,0, ca_fc1_b+d*1536,
        mlpca_buf,1536,0,0, 64,1536,384,1, 1.f, nullptr);
    gemm_f32<false,2><<<dim3(6,1,1),blk,0,stream>>>(mlpca_buf,1536,0,0, ca_fc2_w+(long)d*589824,1536,0,0, ca_fc2_b+d*384,
        cls_buf,384,0,0, 64,384,1536,1, 1.f, ca_g2+d*384);
  }

  // 4. final LN (cls row only matters) + head
  ln_kernel<<<64,128,0,stream>>>(cls_buf, clsln_buf, norm_g, norm_b, 64);
  gemm_f32<false,0><<<dim3(16,1,1),blk,0,stream>>>(clsln_buf,384,0,0, head_w,384,0,0, head_b,
      out,1000,0,0, 64,1000,384,1, 1.f, nullptr);
}

// Round 2
// 5020.992 us; speedup vs baseline: 3.6163x; 3.6163x over previous
//
#include <hip/hip_runtime.h>
#include <hip/hip_bf16.h>
#include <math.h>

#define EPS_ 1e-5f

typedef __attribute__((ext_vector_type(8))) short short8;
typedef __attribute__((ext_vector_type(4))) float f32x4;
typedef unsigned short ushort_t;

__device__ inline ushort_t f2b(float x){
  union{ __hip_bfloat16 h; ushort_t u; } c; c.h = __float2bfloat16(x); return c.u;
}
__device__ inline float b2f(ushort_t u){
  union{ unsigned int i; float f; } c; c.i = ((unsigned int)u)<<16; return c.f;
}
__device__ inline void gload_lds16(const void* g, void* l){
  __builtin_amdgcn_global_load_lds((const __attribute__((address_space(1))) void*)g,
                                   (__attribute__((address_space(3))) void*)l, 16, 0, 0);
}

// ---------------- reduction helpers ----------------
__device__ inline float wred_sum(float v){
#pragma unroll
  for(int o=32;o>=1;o>>=1) v += __shfl_xor(v,o);
  return v;
}
__device__ inline float wred_max(float v){
#pragma unroll
  for(int o=32;o>=1;o>>=1) v = fmaxf(v,__shfl_xor(v,o));
  return v;
}
__device__ inline float bred256_sum(float v, float* sm){
  v = wred_sum(v);
  if((threadIdx.x&63)==0) sm[threadIdx.x>>6]=v;
  __syncthreads();
  v = sm[0]+sm[1]+sm[2]+sm[3];
  __syncthreads();
  return v;
}
__device__ inline float bred256_max(float v, float* sm){
  v = wred_max(v);
  if((threadIdx.x&63)==0) sm[threadIdx.x>>6]=v;
  __syncthreads();
  v = fmaxf(fmaxf(sm[0],sm[1]),fmaxf(sm[2],sm[3]));
  __syncthreads();
  return v;
}

// ---------------- bf16 MFMA GEMM ----------------
// C = A @ W^T.  A:[M,K] bf16 row-major (lda), W:[N,K] bf16 row-major (ldw).
// Batched via blockIdx.z (strides sA, sW in elements).  K % 32 == 0 required.
// 256 threads = 4 waves (2x2).  Tile BM x BN, BK=32, mfma 16x16x32.
// EPI: 0 bf16 store (*alpha, +bias) batched by sC
//      1 f32 store + bias + pos_embed aux[(m%196)*ldc+n]
//      2 f32 residual: C[m,n] += aux[n]*(v+bias[n])
//      3 bf16 store gelu(v+bias)
//      4 qkv scatter: Cv=q [bh][196][64] (*alpha), C2=k same, C3=vT [bh][48][224]
//      5 f32 store batched (attention logits)
//      6 PV scatter: o[(b*196+m)*384 + h*48 + n], z = b*8+h
//      7 f32 store + bias
template<int BM,int BN,int EPI>
__global__ __launch_bounds__(256) void gemm_bf(
    const ushort_t* __restrict__ A, int lda, long sA,
    const ushort_t* __restrict__ W, int ldw, long sW,
    const float* __restrict__ bias,
    void* __restrict__ Cv, int ldc, long sC,
    int M, int N, int K,
    const float* __restrict__ aux,
    void* __restrict__ C2, void* __restrict__ C3,
    float alpha)
{
  constexpr int FM = BM/32, FN = BN/32;
  constexpr int LBM = (BM==128)?7:6;
  constexpr int LBN = (BN==128)?7:6;
  __shared__ ushort_t lA[BM*32];
  __shared__ ushort_t lB[BN*32];
  const int tid = threadIdx.x;
  const int lane = tid & 63, wid = tid >> 6;
  const int wr = wid >> 1, wc = wid & 1;
  const int l15 = lane & 15, l4 = lane >> 4;
  const int z = blockIdx.z;
  const ushort_t* Ab = A + (long)z*sA;
  const ushort_t* Wb = W + (long)z*sW;
  const int m0 = blockIdx.y*BM, n0 = blockIdx.x*BN;

  f32x4 acc[FM][FN];
#pragma unroll
  for(int i=0;i<FM;++i)
#pragma unroll
    for(int j=0;j<FN;++j) acc[i][j] = {0.f,0.f,0.f,0.f};

  for(int k0=0;k0<K;k0+=32){
#pragma unroll
    for(int it=0;it<BM/64;++it){
      int c = it*256 + tid;
      int row = c & (BM-1), kc = c >> LBM;
      int gm = m0+row; gm = gm<M?gm:M-1;
      gload_lds16(Ab + (long)gm*lda + k0 + kc*8, &lA[(it*256 + wid*64)*8]);
    }
#pragma unroll
    for(int it=0;it<BN/64;++it){
      int c = it*256 + tid;
      int row = c & (BN-1), kc = c >> LBN;
      int gn = n0+row; gn = gn<N?gn:N-1;
      gload_lds16(Wb + (long)gn*ldw + k0 + kc*8, &lB[(it*256 + wid*64)*8]);
    }
    __syncthreads();
    short8 a[FM], b[FN];
    const short8* pA = (const short8*)lA;
    const short8* pB = (const short8*)lB;
#pragma unroll
    for(int i=0;i<FM;++i) a[i] = pA[l4*BM + wr*(BM/2) + i*16 + l15];
#pragma unroll
    for(int j=0;j<FN;++j) b[j] = pB[l4*BN + wc*(BN/2) + j*16 + l15];
#pragma unroll
    for(int i=0;i<FM;++i)
#pragma unroll
      for(int j=0;j<FN;++j)
        acc[i][j] = __builtin_amdgcn_mfma_f32_16x16x32_bf16(a[i], b[j], acc[i][j], 0,0,0);
    __syncthreads();
  }

#pragma unroll
  for(int i=0;i<FM;++i){
#pragma unroll
    for(int r=0;r<4;++r){
      int m = m0 + wr*(BM/2) + i*16 + l4*4 + r;
      if(m>=M) continue;
#pragma unroll
      for(int j=0;j<FN;++j){
        int n = n0 + wc*(BN/2) + j*16 + l15;
        if(n>=N) continue;
        float v = acc[i][j][r];
        if(EPI==0){
          v *= alpha; if(bias) v += bias[n];
          ((ushort_t*)Cv)[(long)z*sC + (long)m*ldc + n] = f2b(v);
        } else if(EPI==1){
          ((float*)Cv)[(long)m*ldc+n] = v + bias[n] + aux[(m%196)*ldc + n];
        } else if(EPI==2){
          float* C=(float*)Cv; C[(long)m*ldc+n] += aux[n]*(v+bias[n]);
        } else if(EPI==3){
          v += bias[n];
          v = 0.5f*v*(1.f+erff(v*0.70710678118f));
          ((ushort_t*)Cv)[(long)m*ldc+n] = f2b(v);
        } else if(EPI==4){
          int bq = m/196, p = m - bq*196;
          int which = n/384, nn = n - which*384;
          int hh = nn/48, d = nn - hh*48;
          long bh = bq*8+hh;
          if(which==0)      ((ushort_t*)Cv)[(bh*196+p)*64 + d] = f2b(v*alpha);
          else if(which==1) ((ushort_t*)C2)[(bh*196+p)*64 + d] = f2b(v);
          else              ((ushort_t*)C3)[(bh*48+d)*224 + p] = f2b(v);
        } else if(EPI==5){
          ((float*)Cv)[(long)z*sC + (long)m*ldc + n] = v;
        } else if(EPI==6){
          int bq = z>>3, hh = z&7;
          ((ushort_t*)Cv)[((long)(bq*196+m))*384 + hh*48 + n] = f2b(v);
        } else if(EPI==7){
          ((float*)Cv)[(long)m*ldc+n] = v + bias[n];
        }
      }
    }
  }
}

// ---------------- LayerNorm over 384 cols -> bf16 ----------------
__global__ __launch_bounds__(128) void ln_kernel(
  const float* __restrict__ X, ushort_t* __restrict__ Y,
  const float* __restrict__ g, const float* __restrict__ b, int rows)
{
  int r = blockIdx.x; if(r>=rows) return;
  int t = threadIdx.x;
  const float* xr = X + (long)r*384;
  ushort_t* yr = Y + (long)r*384;
  float x0=xr[t], x1=xr[t+128], x2=xr[t+256];
  __shared__ float sm[2];
  float s = x0+x1+x2;
  s = wred_sum(s);
  if((t&63)==0) sm[t>>6]=s;
  __syncthreads();
  float mean = (sm[0]+sm[1])*(1.f/384.f);
  __syncthreads();
  float d0=x0-mean,d1=x1-mean,d2=x2-mean;
  float ss = d0*d0+d1*d1+d2*d2;
  ss = wred_sum(ss);
  if((t&63)==0) sm[t>>6]=ss;
  __syncthreads();
  float rstd = rsqrtf((sm[0]+sm[1])*(1.f/384.f)+EPS_);
  yr[t]     = f2b(d0*rstd*g[t]    +b[t]);
  yr[t+128] = f2b(d1*rstd*g[t+128]+b[t+128]);
  yr[t+256] = f2b(d2*rstd*g[t+256]+b[t+256]);
}

// ---------------- talking-heads mix + softmax + mix ----------------
// reads fp32 logits [bh][196][196], writes bf16 P padded [bh][196][224]
__global__ __launch_bounds__(256) void th_softmax(
  const float* __restrict__ attn, ushort_t* __restrict__ pb,
  const float* __restrict__ plw, const float* __restrict__ plb,
  const float* __restrict__ pww, const float* __restrict__ pwb)
{
  int bn = blockIdx.x;
  int b = bn/196, n = bn%196;
  int t = threadIdx.x;
  __shared__ float swl[64], sww[64], sbl[8], sbw[8], sm[4];
  if(t<64){ swl[t]=plw[t]; sww[t]=pww[t]; }
  if(t<8){ sbl[t]=plb[t]; sbw[t]=pwb[t]; }
  __syncthreads();
  bool act = t<196;
  long base = (long)b*8*38416 + (long)n*196 + t;
  float L[8];
#pragma unroll
  for(int h=0;h<8;++h) L[h] = act ? attn[base + (long)h*38416] : 0.f;
  float soft[8];
#pragma unroll
  for(int g=0; g<8; ++g){
    float v = sbl[g];
#pragma unroll
    for(int h=0;h<8;++h) v += L[h]*swl[g*8+h];
    if(!act) v = -3.0e38f;
    float mx = bred256_max(v, sm);
    float e = act ? expf(v-mx) : 0.f;
    float ssum = bred256_sum(e, sm);
    soft[g] = e/ssum;
  }
#pragma unroll
  for(int g2=0; g2<8; ++g2){
    float v = sbw[g2];
#pragma unroll
    for(int g=0; g<8; ++g) v += soft[g]*sww[g2*8+g];
    long prow = ((long)(b*8+g2)*196 + n)*224;
    if(t<196) pb[prow + t] = f2b(v);
    else if(t<224) pb[prow + t] = 0;
  }
}

// ---------------- class-attention (1 query token), bf16 in/out ----------------
__global__ __launch_bounds__(256) void ca_attn_kernel(
  const ushort_t* __restrict__ q, const ushort_t* __restrict__ k,
  const ushort_t* __restrict__ v, ushort_t* __restrict__ o)
{
  int bh = blockIdx.x; int b = bh>>3, h = bh&7;
  int t = threadIdx.x;
  __shared__ float qs[48], p[197], sm[4];
  if(t<48) qs[t] = b2f(q[(long)b*384 + h*48 + t]);
  __syncthreads();
  float logit = -3.0e38f;
  if(t<197){
    const ushort_t* kr = k + ((long)(b*197+t))*384 + h*48;
    float s=0.f;
#pragma unroll
    for(int d=0;d<48;++d) s += qs[d]*b2f(kr[d]);
    logit = s;
  }
  float mx = bred256_max(logit, sm);
  float e = (t<197)? expf(logit-mx):0.f;
  float ssum = bred256_sum(e, sm);
  if(t<197) p[t] = e/ssum;
  __syncthreads();
  if(t<48){
    const ushort_t* vr = v + (long)b*197*384 + h*48 + t;
    float s=0.f;
    for(int m=0;m<197;++m) s += p[m]*b2f(vr[(long)m*384]);
    o[(long)b*384 + h*48 + t] = f2b(s);
  }
}

// ---------------- small elementwise kernels ----------------
__global__ void patch_extract(const float* __restrict__ x, ushort_t* __restrict__ xp){
  long i = (long)blockIdx.x*256 + threadIdx.x;
  if(i >= (long)12544*768) return;
  int kk = (int)(i % 768); long row = i/768;
  int b = (int)(row/196), pidx = (int)(row%196);
  int gy = pidx/14, gx = pidx%14;
  int ch = kk/256, r = kk%256, py = r/16, px = r%16;
  xp[i] = f2b(x[((long)(b*3+ch)*224 + gy*16+py)*224 + gx*16+px]);
}
__global__ void build_u(const float* __restrict__ h, float* __restrict__ u){
  long i = (long)blockIdx.x*256 + threadIdx.x;
  if(i >= (long)12544*384) return;
  int c = (int)(i % 384); long rp = i/384;
  int b = (int)(rp/196), p = (int)(rp%196);
  u[((long)b*197 + 1 + p)*384 + c] = h[i];
}
__global__ void set_row0(float* __restrict__ u, const float* __restrict__ cls){
  int i = blockIdx.x*256 + threadIdx.x;
  if(i >= 64*384) return;
  int b = i/384, c = i%384;
  u[(long)b*197*384 + c] = cls[i];
}
__global__ void init_cls(float* __restrict__ cls, const float* __restrict__ tok){
  int i = blockIdx.x*256 + threadIdx.x;
  if(i >= 64*384) return;
  cls[i] = tok[i%384];
}
__global__ void conv_bf(const float* __restrict__ s, ushort_t* __restrict__ d, int n){
  int i = (blockIdx.x*256 + threadIdx.x)*4;
  if(i+3 < n){
    float4 v = *(const float4*)(s+i);
    d[i]=f2b(v.x); d[i+1]=f2b(v.y); d[i+2]=f2b(v.z); d[i+3]=f2b(v.w);
  } else {
    for(int j=i;j<n;++j) d[j]=f2b(s[j]);
  }
}

// ---------------- host orchestration ----------------
extern "C" void kernel_launch(void* const* d_in, const int* in_sizes, int n_in,
                              void* d_out, int out_size, void* d_ws, size_t ws_size,
                              hipStream_t stream)
{
  const float* in_x     = (const float*)d_in[0];
  const float* patch_w  = (const float*)d_in[1];
  const float* patch_b  = (const float*)d_in[2];
  const float* cls_tok  = (const float*)d_in[3];
  const float* pos_emb  = (const float*)d_in[4];
  const float* ln1_g = (const float*)d_in[5];
  const float* ln1_b = (const float*)d_in[6];
  const float* qkv_w = (const float*)d_in[7];
  const float* proj_w = (const float*)d_in[8];
  const float* proj_b = (const float*)d_in[9];
  const float* pl_w = (const float*)d_in[10];
  const float* pl_b = (const float*)d_in[11];
  const float* pw_w = (const float*)d_in[12];
  const float* pw_b = (const float*)d_in[13];
  const float* ln2_g = (const float*)d_in[14];
  const float* ln2_b = (const float*)d_in[15];
  const float* fc1_w = (const float*)d_in[16];
  const float* fc1_b = (const float*)d_in[17];
  const float* fc2_w = (const float*)d_in[18];
  const float* fc2_b = (const float*)d_in[19];
  const float* g1 = (const float*)d_in[20];
  const float* g2 = (const float*)d_in[21];
  const float* ca_ln1_g = (const float*)d_in[22];
  const float* ca_ln1_b = (const float*)d_in[23];
  const float* ca_q_w = (const float*)d_in[24];
  const float* ca_k_w = (const float*)d_in[25];
  const float* ca_v_w = (const float*)d_in[26];
  const float* ca_proj_w = (const float*)d_in[27];
  const float* ca_proj_b = (const float*)d_in[28];
  const float* ca_ln2_g = (const float*)d_in[29];
  const float* ca_ln2_b = (const float*)d_in[30];
  const float* ca_fc1_w = (const float*)d_in[31];
  const float* ca_fc1_b = (const float*)d_in[32];
  const float* ca_fc2_w = (const float*)d_in[33];
  const float* ca_fc2_b = (const float*)d_in[34];
  const float* ca_g1 = (const float*)d_in[35];
  const float* ca_g2 = (const float*)d_in[36];
  const float* norm_g = (const float*)d_in[37];
  const float* norm_b = (const float*)d_in[38];
  const float* head_w = (const float*)d_in[39];
  const float* head_b = (const float*)d_in[40];
  float* out = (float*)d_out;

  char* W0 = (char*)d_ws;
  float*    h_buf  = (float*)   (W0 + 0);          // 12544*384 f32
  float*    attn   = (float*)   (W0 + 19267584);   // 512*196*196 f32 (aliases u, xp)
  float*    u_buf  = attn;
  ushort_t* xp_bf  = (ushort_t*)attn;
  float*    cls    = (float*)   (W0 + 97943552);   // 64*384 f32
  ushort_t* ln_bf  = (ushort_t*)(W0 + 98041856);   // 12608*384 bf16
  ushort_t* qb     = (ushort_t*)(W0 + 107724800);  // 512*196*64 bf16 (aliases o_bf, ca_k)
  ushort_t* kb     = (ushort_t*)(W0 + 120569856);  // 512*196*64 bf16 (aliases ca_v)
  ushort_t* vT     = (ushort_t*)(W0 + 133414912);  // 512*48*224 bf16
  ushort_t* pb     = (ushort_t*)(W0 + 144424960);  // 512*196*224 bf16 (aliases mlp)
  ushort_t* mlp_bf = pb;
  ushort_t* o_bf   = qb;
  ushort_t* ck_bf  = qb;
  ushort_t* cv_bf  = kb;
  ushort_t* wb     = (ushort_t*)(W0 + 189382656);  // 25,451,520 bf16 weights
  ushort_t* cq_bf  = (ushort_t*)(W0 + 240285696);
  ushort_t* oca_bf = (ushort_t*)(W0 + 240334848);
  ushort_t* clsln  = (ushort_t*)(W0 + 240384000);
  ushort_t* mlpca  = (ushort_t*)(W0 + 240433152);

  // weight element offsets inside wb
  const long WP=0, WQKV=294912, WPROJ=5603328, WFC1=7372800, WFC2=14450688,
             WCAQ=21528576, WCAK=21823488, WCAV=22118400, WCAP=22413312,
             WCAF1=22708224, WCAF2=23887872, WHEAD=25067520;

  const float scl = 0.14433756729740643f;  // 48^-0.5
  dim3 blk(256);

  // zero q/k/vT (pads must be exactly 0 for padded-K MFMA)
  hipMemsetAsync(qb, 0, 36700160, stream);

  // convert all weights to bf16
  {
    const float* src[12] = {patch_w,qkv_w,proj_w,fc1_w,fc2_w,ca_q_w,ca_k_w,ca_v_w,
                            ca_proj_w,ca_fc1_w,ca_fc2_w,head_w};
    const long  off[12] = {WP,WQKV,WPROJ,WFC1,WFC2,WCAQ,WCAK,WCAV,WCAP,WCAF1,WCAF2,WHEAD};
    const long  cnt[12] = {294912,5308416,1769472,7077888,7077888,294912,294912,294912,
                           294912,1179648,1179648,384000};
    for(int i=0;i<12;++i)
      conv_bf<<<dim3((unsigned)((cnt[i]/4+255)/256)),blk,0,stream>>>(src[i], wb+off[i], (int)cnt[i]);
  }

  // 1. patch embed
  {
    long n = (long)12544*768;
    patch_extract<<<dim3((unsigned)((n+255)/256)), blk, 0, stream>>>(in_x, xp_bf);
  }
  gemm_bf<128,64,1><<<dim3(6,98,1),blk,0,stream>>>(xp_bf,768,0, wb+WP,768,0, patch_b,
      h_buf,384,0, 12544,384,768, pos_emb, nullptr,nullptr, 1.f);

  // 2. twelve talking-heads SA blocks
  for(int d=0; d<12; ++d){
    ln_kernel<<<12544,128,0,stream>>>(h_buf, ln_bf, ln1_g+d*384, ln1_b+d*384, 12544);
    gemm_bf<128,128,4><<<dim3(9,98,1),blk,0,stream>>>(ln_bf,384,0, wb+WQKV+(long)d*442368,384,0, nullptr,
        qb,0,0, 12544,1152,384, nullptr, kb, vT, scl);
    gemm_bf<64,64,5><<<dim3(4,4,512),blk,0,stream>>>(qb,64,12544, kb,64,12544, nullptr,
        attn,196,38416, 196,196,64, nullptr, nullptr,nullptr, 1.f);
    th_softmax<<<12544,blk,0,stream>>>(attn, pb, pl_w+d*64, pl_b+d*8, pw_w+d*64, pw_b+d*8);
    gemm_bf<64,64,6><<<dim3(1,4,512),blk,0,stream>>>(pb,224,43904, vT,224,10752, nullptr,
        o_bf,0,0, 196,48,224, nullptr, nullptr,nullptr, 1.f);
    gemm_bf<128,64,2><<<dim3(6,98,1),blk,0,stream>>>(o_bf,384,0, wb+WPROJ+(long)d*147456,384,0, proj_b+d*384,
        h_buf,384,0, 12544,384,384, g1+d*384, nullptr,nullptr, 1.f);
    ln_kernel<<<12544,128,0,stream>>>(h_buf, ln_bf, ln2_g+d*384, ln2_b+d*384, 12544);
    gemm_bf<128,128,3><<<dim3(12,98,1),blk,0,stream>>>(ln_bf,384,0, wb+WFC1+(long)d*589824,384,0, fc1_b+d*1536,
        mlp_bf,1536,0, 12544,1536,384, nullptr, nullptr,nullptr, 1.f);
    gemm_bf<128,64,2><<<dim3(6,98,1),blk,0,stream>>>(mlp_bf,1536,0, wb+WFC2+(long)d*589824,1536,0, fc2_b+d*384,
        h_buf,384,0, 12544,384,1536, g2+d*384, nullptr,nullptr, 1.f);
  }

  // 3. two class-attention blocks
  init_cls<<<96,blk,0,stream>>>(cls, cls_tok);
  build_u<<<dim3((unsigned)(((long)12544*384+255)/256)),blk,0,stream>>>(h_buf, u_buf);
  for(int d=0; d<2; ++d){
    set_row0<<<96,blk,0,stream>>>(u_buf, cls);
    ln_kernel<<<12608,128,0,stream>>>(u_buf, ln_bf, ca_ln1_g+d*384, ca_ln1_b+d*384, 12608);
    gemm_bf<64,64,0><<<dim3(6,1,1),blk,0,stream>>>(ln_bf,75648,0, wb+WCAQ+(long)d*147456,384,0, nullptr,
        cq_bf,384,0, 64,384,384, nullptr, nullptr,nullptr, scl);
    gemm_bf<128,64,0><<<dim3(6,99,1),blk,0,stream>>>(ln_bf,384,0, wb+WCAK+(long)d*147456,384,0, nullptr,
        ck_bf,384,0, 12608,384,384, nullptr, nullptr,nullptr, 1.f);
    gemm_bf<128,64,0><<<dim3(6,99,1),blk,0,stream>>>(ln_bf,384,0, wb+WCAV+(long)d*147456,384,0, nullptr,
        cv_bf,384,0, 12608,384,384, nullptr, nullptr,nullptr, 1.f);
    ca_attn_kernel<<<512,blk,0,stream>>>(cq_bf, ck_bf, cv_bf, oca_bf);
    gemm_bf<64,64,2><<<dim3(6,1,1),blk,0,stream>>>(oca_bf,384,0, wb+WCAP+(long)d*147456,384,0, ca_proj_b+d*384,
        cls,384,0, 64,384,384, ca_g1+d*384, nullptr,nullptr, 1.f);
    ln_kernel<<<64,128,0,stream>>>(cls, clsln, ca_ln2_g+d*384, ca_ln2_b+d*384, 64);
    gemm_bf<64,64,3><<<dim3(24,1,1),blk,0,stream>>>(clsln,384,0, wb+WCAF1+(long)d*589824,384,0, ca_fc1_b+d*1536,
        mlpca,1536,0, 64,1536,384, nullptr, nullptr,nullptr, 1.f);
    gemm_bf<64,64,2><<<dim3(6,1,1),blk,0,stream>>>(mlpca,1536,0, wb+WCAF2+(long)d*589824,1536,0, ca_fc2_b+d*384,
        cls,384,0, 64,384,1536, ca_g2+d*384, nullptr,nullptr, 1.f);
  }

  // 4. final LN (cls rows) + head
  ln_kernel<<<64,128,0,stream>>>(cls, clsln, norm_g, norm_b, 64);
  gemm_bf<64,64,7><<<dim3(16,1,1),blk,0,stream>>>(clsln,384,0, wb+WHEAD,384,0, head_b,
      out,1000,0, 64,1000,384, nullptr, nullptr,nullptr, 1.f);
}

// Round 3
// 4348.183 us; speedup vs baseline: 4.1758x; 1.1547x over previous
//
#include <hip/hip_runtime.h>
#include <hip/hip_bf16.h>
#include <math.h>

#define EPS_ 1e-5f

typedef __attribute__((ext_vector_type(8))) short short8;
typedef __attribute__((ext_vector_type(4))) float f32x4;
typedef __attribute__((ext_vector_type(4))) unsigned short us4;
typedef unsigned short ushort_t;

__device__ inline ushort_t f2b(float x){
  union{ __hip_bfloat16 h; ushort_t u; } c; c.h = __float2bfloat16(x); return c.u;
}
__device__ inline float b2f(ushort_t u){
  union{ unsigned int i; float f; } c; c.i = ((unsigned int)u)<<16; return c.f;
}
__device__ inline void gload_lds16(const void* g, void* l){
  __builtin_amdgcn_global_load_lds((const __attribute__((address_space(1))) void*)g,
                                   (__attribute__((address_space(3))) void*)l, 16, 0, 0);
}

// ---------------- reduction helpers ----------------
__device__ inline float wred_sum(float v){
#pragma unroll
  for(int o=32;o>=1;o>>=1) v += __shfl_xor(v,o);
  return v;
}
__device__ inline float wred_max(float v){
#pragma unroll
  for(int o=32;o>=1;o>>=1) v = fmaxf(v,__shfl_xor(v,o));
  return v;
}
__device__ inline float bred256_sum(float v, float* sm){
  v = wred_sum(v);
  if((threadIdx.x&63)==0) sm[threadIdx.x>>6]=v;
  __syncthreads();
  v = sm[0]+sm[1]+sm[2]+sm[3];
  __syncthreads();
  return v;
}
__device__ inline float bred256_max(float v, float* sm){
  v = wred_max(v);
  if((threadIdx.x&63)==0) sm[threadIdx.x>>6]=v;
  __syncthreads();
  v = fmaxf(fmaxf(sm[0],sm[1]),fmaxf(sm[2],sm[3]));
  __syncthreads();
  return v;
}

// ---------------- bf16 MFMA GEMM (BK = 32/64) ----------------
// C = A @ W^T.  A:[M,K] bf16 (lda), W:[N,K] bf16 (ldw). Batched by blockIdx.z.
// 256 threads = 4 waves (2x2). Tile BM x BN, K-step BK, mfma 16x16x32.
// EPI: 0 bf16 store (*alpha, +bias) batched by sC
//      1 f32 store + bias + pos_embed aux[(m%196)*ldc+n]
//      2 f32 residual: C[m,n] += aux[n]*(v+bias[n])
//      3 bf16 store gelu(v+bias)
//      4 qkv scatter: Cv=q [bh][196][64] (*alpha), C2=k same, C3=vT [bh][48][256]
//      6 PV scatter: o[(b*196+m)*384 + h*48 + n], z = b*8+h
//      7 f32 store + bias
template<int BM,int BN,int BK,int EPI>
__global__ __launch_bounds__(256) void gemm_bf(
    const ushort_t* __restrict__ A, int lda, long sA,
    const ushort_t* __restrict__ W, int ldw, long sW,
    const float* __restrict__ bias,
    void* __restrict__ Cv, int ldc, long sC,
    int M, int N, int K,
    const float* __restrict__ aux,
    void* __restrict__ C2, void* __restrict__ C3,
    float alpha)
{
  constexpr int FM = BM/32, FN = BN/32;
  constexpr int LBM = (BM==128)?7:6;
  constexpr int LBN = (BN==128)?7:6;
  __shared__ ushort_t lA[BM*BK];
  __shared__ ushort_t lB[BN*BK];
  const int tid = threadIdx.x;
  const int lane = tid & 63, wid = tid >> 6;
  const int wr = wid >> 1, wc = wid & 1;
  const int l15 = lane & 15, l4 = lane >> 4;
  const int z = blockIdx.z;
  const ushort_t* Ab = A + (long)z*sA;
  const ushort_t* Wb = W + (long)z*sW;
  const int m0 = blockIdx.y*BM, n0 = blockIdx.x*BN;

  f32x4 acc[FM][FN];
#pragma unroll
  for(int i=0;i<FM;++i)
#pragma unroll
    for(int j=0;j<FN;++j) acc[i][j] = {0.f,0.f,0.f,0.f};

  for(int k0=0;k0<K;k0+=BK){
#pragma unroll
    for(int it=0;it<BM*BK/2048;++it){
      int c = it*256 + tid;
      int row = c & (BM-1), kc = c >> LBM;
      int gm = m0+row; gm = gm<M?gm:M-1;
      gload_lds16(Ab + (long)gm*lda + k0 + kc*8, &lA[(it*256 + wid*64)*8]);
    }
#pragma unroll
    for(int it=0;it<BN*BK/2048;++it){
      int c = it*256 + tid;
      int row = c & (BN-1), kc = c >> LBN;
      int gn = n0+row; gn = gn<N?gn:N-1;
      gload_lds16(Wb + (long)gn*ldw + k0 + kc*8, &lB[(it*256 + wid*64)*8]);
    }
    __syncthreads();
    const short8* pA = (const short8*)lA;
    const short8* pB = (const short8*)lB;
#pragma unroll
    for(int ks=0;ks<BK/32;++ks){
      short8 a[FM], b[FN];
#pragma unroll
      for(int i=0;i<FM;++i) a[i] = pA[(ks*4+l4)*BM + wr*(BM/2) + i*16 + l15];
#pragma unroll
      for(int j=0;j<FN;++j) b[j] = pB[(ks*4+l4)*BN + wc*(BN/2) + j*16 + l15];
#pragma unroll
      for(int i=0;i<FM;++i)
#pragma unroll
        for(int j=0;j<FN;++j)
          acc[i][j] = __builtin_amdgcn_mfma_f32_16x16x32_bf16(a[i], b[j], acc[i][j], 0,0,0);
    }
    __syncthreads();
  }

#pragma unroll
  for(int i=0;i<FM;++i){
#pragma unroll
    for(int r=0;r<4;++r){
      int m = m0 + wr*(BM/2) + i*16 + l4*4 + r;
      if(m>=M) continue;
#pragma unroll
      for(int j=0;j<FN;++j){
        int n = n0 + wc*(BN/2) + j*16 + l15;
        if(n>=N) continue;
        float v = acc[i][j][r];
        if(EPI==0){
          v *= alpha; if(bias) v += bias[n];
          ((ushort_t*)Cv)[(long)z*sC + (long)m*ldc + n] = f2b(v);
        } else if(EPI==1){
          ((float*)Cv)[(long)m*ldc+n] = v + bias[n] + aux[(m%196)*ldc + n];
        } else if(EPI==2){
          float* C=(float*)Cv; C[(long)m*ldc+n] += aux[n]*(v+bias[n]);
        } else if(EPI==3){
          v += bias[n];
          v = 0.5f*v*(1.f+erff(v*0.70710678118f));
          ((ushort_t*)Cv)[(long)m*ldc+n] = f2b(v);
        } else if(EPI==4){
          int bq = m/196, p = m - bq*196;
          int which = n/384, nn = n - which*384;
          int hh = nn/48, d = nn - hh*48;
          long bh = bq*8+hh;
          if(which==0)      ((ushort_t*)Cv)[(bh*196+p)*64 + d] = f2b(v*alpha);
          else if(which==1) ((ushort_t*)C2)[(bh*196+p)*64 + d] = f2b(v);
          else              ((ushort_t*)C3)[(bh*48+d)*256 + p] = f2b(v);
        } else if(EPI==6){
          int bq = z>>3, hh = z&7;
          ((ushort_t*)Cv)[((long)(bq*196+m))*384 + hh*48 + n] = f2b(v);
        } else if(EPI==7){
          ((float*)Cv)[(long)m*ldc+n] = v + bias[n];
        }
      }
    }
  }
}

// ---------------- LayerNorm over 384 cols -> bf16 ----------------
__global__ __launch_bounds__(128) void ln_kernel(
  const float* __restrict__ X, ushort_t* __restrict__ Y,
  const float* __restrict__ g, const float* __restrict__ b, int rows)
{
  int r = blockIdx.x; if(r>=rows) return;
  int t = threadIdx.x;
  const float* xr = X + (long)r*384;
  ushort_t* yr = Y + (long)r*384;
  float x0=xr[t], x1=xr[t+128], x2=xr[t+256];
  __shared__ float sm[2];
  float s = x0+x1+x2;
  s = wred_sum(s);
  if((t&63)==0) sm[t>>6]=s;
  __syncthreads();
  float mean = (sm[0]+sm[1])*(1.f/384.f);
  __syncthreads();
  float d0=x0-mean,d1=x1-mean,d2=x2-mean;
  float ss = d0*d0+d1*d1+d2*d2;
  ss = wred_sum(ss);
  if((t&63)==0) sm[t>>6]=ss;
  __syncthreads();
  float rstd = rsqrtf((sm[0]+sm[1])*(1.f/384.f)+EPS_);
  yr[t]     = f2b(d0*rstd*g[t]    +b[t]);
  yr[t+128] = f2b(d1*rstd*g[t+128]+b[t+128]);
  yr[t+256] = f2b(d2*rstd*g[t+256]+b[t+256]);
}

// ---------------- talking-heads mix + softmax + mix, in place ----------------
// attn: bf16 [b*8+h][196][256]; one WAVE per (b,n) row; lane holds 4 consecutive cols.
// Reads logits for all 8 heads, writes mixed softmax P (cols>=196 zeroed).
__global__ __launch_bounds__(256) void th_softmax(
  ushort_t* attn,
  const float* __restrict__ plw, const float* __restrict__ plb,
  const float* __restrict__ pww, const float* __restrict__ pwb)
{
  __shared__ float swl[64], sww[64], sbl[8], sbw[8];
  int t = threadIdx.x;
  if(t<64){ swl[t]=plw[t]; sww[t]=pww[t]; }
  if(t<8){ sbl[t]=plb[t]; sbw[t]=pwb[t]; }
  __syncthreads();
  int wid = t>>6, lane = t&63;
  int rid = blockIdx.x*4 + wid;
  int b = rid/196, n = rid - b*196;
  long rbase = ((long)(b*8)*196 + n)*256;
  int col0 = lane*4;
  bool ac[4];
#pragma unroll
  for(int c=0;c<4;++c) ac[c] = (col0+c)<196;
  float L[8][4];
#pragma unroll
  for(int h=0;h<8;++h){
    us4 v = *(const us4*)(attn + rbase + (long)h*50176 + col0);
#pragma unroll
    for(int c=0;c<4;++c) L[h][c] = b2f(v[c]);
  }
  float P[8][4];
#pragma unroll
  for(int g=0; g<8; ++g){
    float mv[4];
#pragma unroll
    for(int c=0;c<4;++c){
      float v = sbl[g];
#pragma unroll
      for(int h=0;h<8;++h) v += L[h][c]*swl[g*8+h];
      mv[c] = ac[c] ? v : -3.0e38f;
    }
    float mx = fmaxf(fmaxf(mv[0],mv[1]),fmaxf(mv[2],mv[3]));
    mx = wred_max(mx);
    float sum = 0.f;
#pragma unroll
    for(int c=0;c<4;++c){
      float e = ac[c] ? exp2f((mv[c]-mx)*1.4426950408889634f) : 0.f;
      P[g][c] = e; sum += e;
    }
    sum = wred_sum(sum);
    float rinv = 1.f/sum;
#pragma unroll
    for(int c=0;c<4;++c) P[g][c] *= rinv;
  }
#pragma unroll
  for(int g2=0; g2<8; ++g2){
    us4 st;
#pragma unroll
    for(int c=0;c<4;++c){
      float v = sbw[g2];
#pragma unroll
      for(int g=0; g<8; ++g) v += P[g][c]*sww[g2*8+g];
      st[c] = ac[c] ? f2b(v) : (ushort_t)0;
    }
    *(us4*)(attn + ((long)(b*8+g2)*196 + n)*256 + col0) = st;
  }
}

// ---------------- class-attention (1 query token), bf16 in/out ----------------
__global__ __launch_bounds__(256) void ca_attn_kernel(
  const ushort_t* __restrict__ q, const ushort_t* __restrict__ k,
  const ushort_t* __restrict__ v, ushort_t* __restrict__ o)
{
  int bh = blockIdx.x; int b = bh>>3, h = bh&7;
  int t = threadIdx.x;
  __shared__ float qs[48], p[197], sm[4];
  if(t<48) qs[t] = b2f(q[(long)b*384 + h*48 + t]);
  __syncthreads();
  float logit = -3.0e38f;
  if(t<197){
    const ushort_t* kr = k + ((long)(b*197+t))*384 + h*48;
    float s=0.f;
#pragma unroll
    for(int d=0;d<48;++d) s += qs[d]*b2f(kr[d]);
    logit = s;
  }
  float mx = bred256_max(logit, sm);
  float e = (t<197)? expf(logit-mx):0.f;
  float ssum = bred256_sum(e, sm);
  if(t<197) p[t] = e/ssum;
  __syncthreads();
  if(t<48){
    const ushort_t* vr = v + (long)b*197*384 + h*48 + t;
    float s=0.f;
    for(int m=0;m<197;++m) s += p[m]*b2f(vr[(long)m*384]);
    o[(long)b*384 + h*48 + t] = f2b(s);
  }
}

// ---------------- small elementwise kernels ----------------
__global__ void patch_extract(const float* __restrict__ x, ushort_t* __restrict__ xp){
  long i = (long)blockIdx.x*256 + threadIdx.x;
  if(i >= (long)12544*768) return;
  int kk = (int)(i % 768); long row = i/768;
  int b = (int)(row/196), pidx = (int)(row%196);
  int gy = pidx/14, gx = pidx%14;
  int ch = kk/256, r = kk%256, py = r/16, px = r%16;
  xp[i] = f2b(x[((long)(b*3+ch)*224 + gy*16+py)*224 + gx*16+px]);
}
__global__ void build_u(const float* __restrict__ h, float* __restrict__ u){
  long i = (long)blockIdx.x*256 + threadIdx.x;
  if(i >= (long)12544*384) return;
  int c = (int)(i % 384); long rp = i/384;
  int b = (int)(rp/196), p = (int)(rp%196);
  u[((long)b*197 + 1 + p)*384 + c] = h[i];
}
__global__ void set_row0(float* __restrict__ u, const float* __restrict__ cls){
  int i = blockIdx.x*256 + threadIdx.x;
  if(i >= 64*384) return;
  int b = i/384, c = i%384;
  u[(long)b*197*384 + c] = cls[i];
}
__global__ void init_cls(float* __restrict__ cls, const float* __restrict__ tok){
  int i = blockIdx.x*256 + threadIdx.x;
  if(i >= 64*384) return;
  cls[i] = tok[i%384];
}
__global__ void conv_bf(const float* __restrict__ s, ushort_t* __restrict__ d, int n){
  int i = (blockIdx.x*256 + threadIdx.x)*4;
  if(i+3 < n){
    float4 v = *(const float4*)(s+i);
    d[i]=f2b(v.x); d[i+1]=f2b(v.y); d[i+2]=f2b(v.z); d[i+3]=f2b(v.w);
  } else {
    for(int j=i;j<n;++j) d[j]=f2b(s[j]);
  }
}

// ---------------- host orchestration ----------------
extern "C" void kernel_launch(void* const* d_in, const int* in_sizes, int n_in,
                              void* d_out, int out_size, void* d_ws, size_t ws_size,
                              hipStream_t stream)
{
  const float* in_x     = (const float*)d_in[0];
  const float* patch_w  = (const float*)d_in[1];
  const float* patch_b  = (const float*)d_in[2];
  const float* cls_tok  = (const float*)d_in[3];
  const float* pos_emb  = (const float*)d_in[4];
  const float* ln1_g = (const float*)d_in[5];
  const float* ln1_b = (const float*)d_in[6];
  const float* qkv_w = (const float*)d_in[7];
  const float* proj_w = (const float*)d_in[8];
  const float* proj_b = (const float*)d_in[9];
  const float* pl_w = (const float*)d_in[10];
  const float* pl_b = (const float*)d_in[11];
  const float* pw_w = (const float*)d_in[12];
  const float* pw_b = (const float*)d_in[13];
  const float* ln2_g = (const float*)d_in[14];
  const float* ln2_b = (const float*)d_in[15];
  const float* fc1_w = (const float*)d_in[16];
  const float* fc1_b = (const float*)d_in[17];
  const float* fc2_w = (const float*)d_in[18];
  const float* fc2_b = (const float*)d_in[19];
  const float* g1 = (const float*)d_in[20];
  const float* g2 = (const float*)d_in[21];
  const float* ca_ln1_g = (const float*)d_in[22];
  const float* ca_ln1_b = (const float*)d_in[23];
  const float* ca_q_w = (const float*)d_in[24];
  const float* ca_k_w = (const float*)d_in[25];
  const float* ca_v_w = (const float*)d_in[26];
  const float* ca_proj_w = (const float*)d_in[27];
  const float* ca_proj_b = (const float*)d_in[28];
  const float* ca_ln2_g = (const float*)d_in[29];
  const float* ca_ln2_b = (const float*)d_in[30];
  const float* ca_fc1_w = (const float*)d_in[31];
  const float* ca_fc1_b = (const float*)d_in[32];
  const float* ca_fc2_w = (const float*)d_in[33];
  const float* ca_fc2_b = (const float*)d_in[34];
  const float* ca_g1 = (const float*)d_in[35];
  const float* ca_g2 = (const float*)d_in[36];
  const float* norm_g = (const float*)d_in[37];
  const float* norm_b = (const float*)d_in[38];
  const float* head_w = (const float*)d_in[39];
  const float* head_b = (const float*)d_in[40];
  float* out = (float*)d_out;

  // ---- workspace layout (bytes) ----
  char* W0 = (char*)d_ws;
  float*    h_buf  = (float*)   (W0 + 0);          // 12544*384 f32 = 19,267,584
  // region B (51,380,224 B): attn/P bf16 [512][196][256]  |  u f32 [12608][384]
  //                          | xp bf16 [12544][768] | mlp bf16 [12544][1536]
  ushort_t* attn   = (ushort_t*)(W0 + 19267584);
  float*    u_buf  = (float*)attn;
  ushort_t* xp_bf  = (ushort_t*)attn;
  ushort_t* mlp_bf = (ushort_t*)attn;
  float*    cls    = (float*)   (W0 + 70647808);   // 64*384 f32
  ushort_t* ln_bf  = (ushort_t*)(W0 + 70746112);   // 12608*384 bf16
  ushort_t* qb     = (ushort_t*)(W0 + 80429056);   // 512*196*64 bf16 (aliases o_bf, ca_k)
  ushort_t* kb     = (ushort_t*)(W0 + 93274112);   // 512*196*64 bf16 (aliases ca_v)
  ushort_t* vT     = (ushort_t*)(W0 + 106119168);  // 512*48*256 bf16
  ushort_t* wb     = (ushort_t*)(W0 + 118702080);  // 25,451,520 bf16 weights
  ushort_t* cq_bf  = (ushort_t*)(W0 + 169605120);
  ushort_t* oca_bf = (ushort_t*)(W0 + 169654272);
  ushort_t* clsln  = (ushort_t*)(W0 + 169703424);
  ushort_t* mlpca  = (ushort_t*)(W0 + 169752576);
  ushort_t* o_bf   = qb;
  ushort_t* ck_bf  = qb;
  ushort_t* cv_bf  = kb;

  const long WP=0, WQKV=294912, WPROJ=5603328, WFC1=7372800, WFC2=14450688,
             WCAQ=21528576, WCAK=21823488, WCAV=22118400, WCAP=22413312,
             WCAF1=22708224, WCAF2=23887872, WHEAD=25067520;

  const float scl = 0.14433756729740643f;  // 48^-0.5
  dim3 blk(256);

  // zero q/k/vT pads (one contiguous region)
  hipMemsetAsync(qb, 0, 38273024, stream);

  // convert all weights to bf16
  {
    const float* src[12] = {patch_w,qkv_w,proj_w,fc1_w,fc2_w,ca_q_w,ca_k_w,ca_v_w,
                            ca_proj_w,ca_fc1_w,ca_fc2_w,head_w};
    const long  off[12] = {WP,WQKV,WPROJ,WFC1,WFC2,WCAQ,WCAK,WCAV,WCAP,WCAF1,WCAF2,WHEAD};
    const long  cnt[12] = {294912,5308416,1769472,7077888,7077888,294912,294912,294912,
                           294912,1179648,1179648,384000};
    for(int i=0;i<12;++i)
      conv_bf<<<dim3((unsigned)((cnt[i]/4+255)/256)),blk,0,stream>>>(src[i], wb+off[i], (int)cnt[i]);
  }

  // 1. patch embed
  {
    long n = (long)12544*768;
    patch_extract<<<dim3((unsigned)((n+255)/256)), blk, 0, stream>>>(in_x, xp_bf);
  }
  gemm_bf<128,64,64,1><<<dim3(6,98,1),blk,0,stream>>>(xp_bf,768,0, wb+WP,768,0, patch_b,
      h_buf,384,0, 12544,384,768, pos_emb, nullptr,nullptr, 1.f);

  // 2. twelve talking-heads SA blocks
  for(int d=0; d<12; ++d){
    ln_kernel<<<12544,128,0,stream>>>(h_buf, ln_bf, ln1_g+d*384, ln1_b+d*384, 12544);
    gemm_bf<128,128,64,4><<<dim3(9,98,1),blk,0,stream>>>(ln_bf,384,0, wb+WQKV+(long)d*442368,384,0, nullptr,
        qb,0,0, 12544,1152,384, nullptr, kb, vT, scl);
    // logits (bf16, in attn [bh][196][256]); single K-step
    gemm_bf<64,64,64,0><<<dim3(4,4,512),blk,0,stream>>>(qb,64,12544, kb,64,12544, nullptr,
        attn,256,50176, 196,196,64, nullptr, nullptr,nullptr, 1.f);
    th_softmax<<<3136,blk,0,stream>>>(attn, pl_w+d*64, pl_b+d*8, pw_w+d*64, pw_b+d*8);
    // o = P @ V   (P rows 196 x K=256 padded, vT [48][256])
    gemm_bf<64,64,64,6><<<dim3(1,4,512),blk,0,stream>>>(attn,256,50176, vT,256,12288, nullptr,
        o_bf,0,0, 196,48,256, nullptr, nullptr,nullptr, 1.f);
    gemm_bf<128,64,64,2><<<dim3(6,98,1),blk,0,stream>>>(o_bf,384,0, wb+WPROJ+(long)d*147456,384,0, proj_b+d*384,
        h_buf,384,0, 12544,384,384, g1+d*384, nullptr,nullptr, 1.f);
    ln_kernel<<<12544,128,0,stream>>>(h_buf, ln_bf, ln2_g+d*384, ln2_b+d*384, 12544);
    gemm_bf<128,128,64,3><<<dim3(12,98,1),blk,0,stream>>>(ln_bf,384,0, wb+WFC1+(long)d*589824,384,0, fc1_b+d*1536,
        mlp_bf,1536,0, 12544,1536,384, nullptr, nullptr,nullptr, 1.f);
    gemm_bf<128,64,64,2><<<dim3(6,98,1),blk,0,stream>>>(mlp_bf,1536,0, wb+WFC2+(long)d*589824,1536,0, fc2_b+d*384,
        h_buf,384,0, 12544,384,1536, g2+d*384, nullptr,nullptr, 1.f);
  }

  // 3. two class-attention blocks
  init_cls<<<96,blk,0,stream>>>(cls, cls_tok);
  build_u<<<dim3((unsigned)(((long)12544*384+255)/256)),blk,0,stream>>>(h_buf, u_buf);
  for(int d=0; d<2; ++d){
    set_row0<<<96,blk,0,stream>>>(u_buf, cls);
    ln_kernel<<<12608,128,0,stream>>>(u_buf, ln_bf, ca_ln1_g+d*384, ca_ln1_b+d*384, 12608);
    gemm_bf<64,64,64,0><<<dim3(6,1,1),blk,0,stream>>>(ln_bf,75648,0, wb+WCAQ+(long)d*147456,384,0, nullptr,
        cq_bf,384,0, 64,384,384, nullptr, nullptr,nullptr, scl);
    gemm_bf<128,64,64,0><<<dim3(6,99,1),blk,0,stream>>>(ln_bf,384,0, wb+WCAK+(long)d*147456,384,0, nullptr,
        ck_bf,384,0, 12608,384,384, nullptr, nullptr,nullptr, 1.f);
    gemm_bf<128,64,64,0><<<dim3(6,99,1),blk,0,stream>>>(ln_bf,384,0, wb+WCAV+(long)d*147456,384,0, nullptr,
        cv_bf,384,0, 12608,384,384, nullptr, nullptr,nullptr, 1.f);
    ca_attn_kernel<<<512,blk,0,stream>>>(cq_bf, ck_bf, cv_bf, oca_bf);
    gemm_bf<64,64,64,2><<<dim3(6,1,1),blk,0,stream>>>(oca_bf,384,0, wb+WCAP+(long)d*147456,384,0, ca_proj_b+d*384,
        cls,384,0, 64,384,384, ca_g1+d*384, nullptr,nullptr, 1.f);
    ln_kernel<<<64,128,0,stream>>>(cls, clsln, ca_ln2_g+d*384, ca_ln2_b+d*384, 64);
    gemm_bf<64,64,64,3><<<dim3(24,1,1),blk,0,stream>>>(clsln,384,0, wb+WCAF1+(long)d*589824,384,0, ca_fc1_b+d*1536,
        mlpca,1536,0, 64,1536,384, nullptr, nullptr,nullptr, 1.f);
    gemm_bf<64,64,64,2><<<dim3(6,1,1),blk,0,stream>>>(mlpca,1536,0, wb+WCAF2+(long)d*589824,1536,0, ca_fc2_b+d*384,
        cls,384,0, 64,384,1536, ca_g2+d*384, nullptr,nullptr, 1.f);
  }

  // 4. final LN (cls rows) + head
  ln_kernel<<<64,128,0,stream>>>(cls, clsln, norm_g, norm_b, 64);
  gemm_bf<64,64,64,7><<<dim3(16,1,1),blk,0,stream>>>(clsln,384,0, wb+WHEAD,384,0, head_b,
      out,1000,0, 64,1000,384, nullptr, nullptr,nullptr, 1.f);
}